// Round 24
// baseline (591.684 us; speedup 1.0000x reference)
//
#include <hip/hip_runtime.h>
#include <hip/hip_bf16.h>
#include <math.h>

typedef float f32x4 __attribute__((ext_vector_type(4)));
typedef __bf16 bf16x8 __attribute__((ext_vector_type(8)));

#define NTOK 98
#define NWIN 2048
#define NN (NTOK * NTOK)            // 9604
#define SCALE 0.17677669529663689f
#define MROWS (NWIN * NTOK)         // 200704
#define PSTRIDE 9408                // per-(win,h): q 3136 + k 3136 + v 3136 elems

// ---------------- async global->LDS 16B ----------------
__device__ __forceinline__ void g2l16(const void* g, void* l) {
  typedef __attribute__((address_space(1))) const unsigned int GU;
  typedef __attribute__((address_space(3))) unsigned int LU;
  __builtin_amdgcn_global_load_lds((GU*)g, (LU*)l, 16, 0, 0);
}

// ---------------- prep (vectorized): weights->bf16, cmb float4 ----------------
__global__ void prep_kernel(const float* __restrict__ qkv_w, const float* __restrict__ proj_w,
                            const float* __restrict__ pbt, const int* __restrict__ rpi,
                            const float* __restrict__ mask,
                            __bf16* __restrict__ qkvw_b, __bf16* __restrict__ projw_b,
                            float* __restrict__ cmb) {
  int i4 = blockIdx.x * 256 + threadIdx.x;
  // weight conversion: 8 floats per thread
  if (i4 < 768 * 256 / 8) {
    const float* p = qkv_w + (size_t)i4 * 8;
    float4 f0 = *(const float4*)p;
    float4 f1 = *(const float4*)(p + 4);
    bf16x8 hv;
    hv[0] = (__bf16)f0.x; hv[1] = (__bf16)f0.y; hv[2] = (__bf16)f0.z; hv[3] = (__bf16)f0.w;
    hv[4] = (__bf16)f1.x; hv[5] = (__bf16)f1.y; hv[6] = (__bf16)f1.z; hv[7] = (__bf16)f1.w;
    *(bf16x8*)(qkvw_b + (size_t)i4 * 8) = hv;
  }
  if (i4 < 256 * 256 / 8) {
    const float* p = proj_w + (size_t)i4 * 8;
    float4 f0 = *(const float4*)p;
    float4 f1 = *(const float4*)(p + 4);
    bf16x8 hv;
    hv[0] = (__bf16)f0.x; hv[1] = (__bf16)f0.y; hv[2] = (__bf16)f0.z; hv[3] = (__bf16)f0.w;
    hv[4] = (__bf16)f1.x; hv[5] = (__bf16)f1.y; hv[6] = (__bf16)f1.z; hv[7] = (__bf16)f1.w;
    *(bf16x8*)(projw_b + (size_t)i4 * 8) = hv;
  }
  // cmb: one float4 per thread
  if (i4 < 256 * 8 * NTOK * 32) {
    int mh = i4 / (NTOK * 32);            // m*8 + h
    int rem = i4 - mh * (NTOK * 32);
    int row = rem >> 5, j4 = rem & 31;
    int j = j4 * 4;
    int m = mh >> 3, h = mh & 7;
    float4 v = {0.f, 0.f, 0.f, 0.f};
    if (j < NTOK) {
      const float* mrow = mask + (size_t)m * NN + row * NTOK;
      const int* rrow = rpi + row * NTOK;
#pragma unroll
      for (int c = 0; c < 4; ++c)
        if (j + c < NTOK) (&v.x)[c] = pbt[rrow[j + c] * 8 + h] + mrow[j + c];
    }
    *(float4*)(cmb + (size_t)(mh * NTOK + row) * 128 + j) = v;
  }
}

// ---------------- QKV GEMM: A once in LDS; B reg-pipelined from L2; NO K-loop barriers ----------------
__launch_bounds__(256)
__global__ void gemm_qkv(const float* __restrict__ A, const __bf16* __restrict__ W,
                         __bf16* __restrict__ C) {
  __shared__ __align__(16) char As[65536];       // [128 rows][256 bf16] swizzled
  const int m0 = blockIdx.x * 128;
  const int tid = threadIdx.x;
  const int lane = tid & 63;
  const int wid = tid >> 6;
  const int wm = wid & 1, wn = wid >> 1;         // 2M x 2N waves, 64x64 each
  const int lr = lane & 15;
  const int lg = lane >> 4;

  // stage A once: fp32 -> bf16 through regs, swizzled, K fully resident
  for (int c = tid; c < 128 * 32; c += 256) {
    int row = c >> 5, slot = c & 31;
    const float* ap = A + (size_t)(m0 + row) * 256 + slot * 8;
    float4 f0 = *(const float4*)ap;
    float4 f1 = *(const float4*)(ap + 4);
    bf16x8 hv;
    hv[0] = (__bf16)f0.x; hv[1] = (__bf16)f0.y; hv[2] = (__bf16)f0.z; hv[3] = (__bf16)f0.w;
    hv[4] = (__bf16)f1.x; hv[5] = (__bf16)f1.y; hv[6] = (__bf16)f1.z; hv[7] = (__bf16)f1.w;
    *(bf16x8*)(As + row * 512 + ((slot * 16) ^ ((row & 7) << 4))) = hv;
  }
  __syncthreads();   // the ONLY barrier

  for (int nt = 0; nt < 6; ++nt) {
    const int n0 = nt * 128;
    f32x4 acc[4][4] = {};

    // prefetch B for ks=0 into registers
    bf16x8 bcur[4];
#pragma unroll
    for (int n = 0; n < 4; ++n)
      bcur[n] = *(const bf16x8*)(W + (size_t)(n0 + wn * 64 + n * 16 + lr) * 256 + lg * 8);

#pragma unroll
    for (int ks = 0; ks < 8; ++ks) {
      bf16x8 bnext[4];
      if (ks < 7) {
#pragma unroll
        for (int n = 0; n < 4; ++n)
          bnext[n] = *(const bf16x8*)(W + (size_t)(n0 + wn * 64 + n * 16 + lr) * 256 +
                                      (ks + 1) * 32 + lg * 8);
      }
      bf16x8 a[4];
#pragma unroll
      for (int m = 0; m < 4; ++m) {
        int row = wm * 64 + m * 16 + lr;
        a[m] = *(const bf16x8*)(As + row * 512 + ((ks * 64 + lg * 16) ^ ((row & 7) << 4)));
      }
#pragma unroll
      for (int m = 0; m < 4; ++m)
#pragma unroll
        for (int n = 0; n < 4; ++n)
          acc[m][n] = __builtin_amdgcn_mfma_f32_16x16x32_bf16(a[m], bcur[n], acc[m][n], 0, 0, 0);
      if (ks < 7) {
#pragma unroll
        for (int n = 0; n < 4; ++n) bcur[n] = bnext[n];
      }
    }

    // epilogue for this nt: head-blocked, linear [tok][32] -> coalesced 32B stores
#pragma unroll
    for (int m = 0; m < 4; ++m)
#pragma unroll
      for (int r = 0; r < 4; ++r) {
        unsigned row = m0 + wm * 64 + m * 16 + lg * 4 + r;
        unsigned win = row / NTOK;
        unsigned tok = row - win * NTOK;
#pragma unroll
        for (int n = 0; n < 4; ++n) {
          int col = n0 + wn * 64 + n * 16 + lr;
          int sec = col >> 8, dd = col & 255;
          int h = dd >> 5, d = dd & 31;
          C[(size_t)(win * 8 + h) * PSTRIDE + (size_t)sec * 3136 + tok * 32 + d] =
              (__bf16)acc[m][n][r];
        }
      }
  }
}

// ---------------- attention (R14): cmb float4 stream; VT in LDS; hoisted K frags ----------------
__launch_bounds__(128)
__global__ void attn_kernel(const __bf16* __restrict__ qkv, const float* __restrict__ cmb,
                            __bf16* __restrict__ y) {
  __shared__ __align__(16) char VTB[8192];      // VT [32 d][128 j] bf16, swizzled
  int bx = blockIdx.x;
  int lb = (bx & 7) * 2048 + (bx >> 3);         // win-major within each XCD
  const int win = lb >> 3, h = lb & 7;
  const int tid = threadIdx.x;
  const int lane = tid & 63, wv = tid >> 6;
  const int lr = lane & 15, lg = lane >> 4;
  const f32x4 fz = {0.f, 0.f, 0.f, 0.f};

  const __bf16* qw = qkv + (size_t)(win * 8 + h) * PSTRIDE;
  const __bf16* kw = qw + 3136;
  const __bf16* vw = qw + 6272;                 // v [tok][32]
  const float* cw = cmb + (size_t)((win & 255) * 8 + h) * (NTOK * 128);

  for (int c = tid; c < 512; c += 128) {
    int j = c & 127; int jc = j < NTOK ? j : NTOK - 1;
    int d8 = (c >> 7) << 3;
    bf16x8 vv = *(const bf16x8*)(vw + jc * 32 + d8);
#pragma unroll
    for (int e = 0; e < 8; ++e) {
      int d = d8 + e;
      *(__bf16*)(VTB + d * 256 + ((2 * j) ^ ((d & 7) << 4))) = vv[e];
    }
  }

  bf16x8 bk[7];
#pragma unroll
  for (int jt = 0; jt < 7; ++jt) {
    int brow = ((jt >> 1) << 5) + ((lr >> 2) << 3) + ((jt & 1) << 2) + (lr & 3);
    int browc = brow < NTOK ? brow : NTOK - 1;
    bk[jt] = *(const bf16x8*)(kw + browc * 32 + lg * 8);
  }
  __syncthreads();

  for (int it = wv; it < 7; it += 2) {
    const int i0 = it * 16;
    const int qrow = i0 + lr;
    const int qrowc = qrow < NTOK ? qrow : NTOK - 1;
    bf16x8 aq = *(const bf16x8*)(qw + qrowc * 32 + lg * 8);

    const float* cr = cw + qrowc * 128;
    float4 cv[7];
#pragma unroll
    for (int jt = 0; jt < 7; ++jt) {
      int kb = ((jt >> 1) << 5) + lg * 8 + ((jt & 1) << 2);
      cv[jt] = *(const float4*)(cr + kb);
    }

    f32x4 s[7];
#pragma unroll
    for (int jt = 0; jt < 7; ++jt)
      s[jt] = __builtin_amdgcn_mfma_f32_16x16x32_bf16(bk[jt], aq, fz, 0, 0, 0);

    float sv[7][4];
    float mx = -INFINITY;
#pragma unroll
    for (int jt = 0; jt < 7; ++jt) {
      int kb = ((jt >> 1) << 5) + lg * 8 + ((jt & 1) << 2);
#pragma unroll
      for (int r = 0; r < 4; ++r) {
        float xv = (kb + r < NTOK) ? fmaf(SCALE, s[jt][r], (&cv[jt].x)[r]) : -INFINITY;
        sv[jt][r] = xv;
        mx = fmaxf(mx, xv);
      }
    }
    mx = fmaxf(mx, __shfl_xor(mx, 16));
    mx = fmaxf(mx, __shfl_xor(mx, 32));
    float sum = 0.f;
#pragma unroll
    for (int jt = 0; jt < 7; ++jt)
#pragma unroll
      for (int r = 0; r < 4; ++r) {
        float p = __expf(sv[jt][r] - mx);
        sv[jt][r] = p;
        sum += p;
      }
    sum += __shfl_xor(sum, 16);
    sum += __shfl_xor(sum, 32);
    const float rinv = 1.f / sum;

    bf16x8 pa[4];
#pragma unroll
    for (int ks = 0; ks < 4; ++ks)
#pragma unroll
      for (int e = 0; e < 8; ++e) {
        int jt = 2 * ks + (e >> 2);
        pa[ks][e] = (jt < 7) ? (__bf16)sv[jt][e & 3] : (__bf16)0.f;
      }

    float rv[4];
#pragma unroll
    for (int r = 0; r < 4; ++r) rv[r] = __shfl(rinv, lg * 4 + r);

#pragma unroll
    for (int dt = 0; dt < 2; ++dt) {
      f32x4 o = fz;
#pragma unroll
      for (int ks = 0; ks < 4; ++ks) {
        int vrow = dt * 16 + lr;
        bf16x8 vb = *(const bf16x8*)(VTB + vrow * 256 + ((ks * 64 + lg * 16) ^ ((vrow & 7) << 4)));
        o = __builtin_amdgcn_mfma_f32_16x16x32_bf16(pa[ks], vb, o, 0, 0, 0);
      }
#pragma unroll
      for (int r = 0; r < 4; ++r) {
        int row = i0 + lg * 4 + r;
        if (row < NTOK)
          y[((size_t)win * NTOK + row) * 256 + h * 32 + dt * 16 + lr] = (__bf16)(o[r] * rv[r]);
      }
    }
  }
}

// ---------------- proj GEMM (R20): A(y) staged once, 2 N-tiles per block, B dbuf BK=32 ----------------
__launch_bounds__(256)
__global__ void gemm_proj(const __bf16* __restrict__ A, const __bf16* __restrict__ W,
                          const float* __restrict__ pb, float* __restrict__ C) {
  __shared__ __align__(16) char As[65536];       // [128 rows][256 bf16] swizzled
  __shared__ __align__(16) char Bs[2][8192];     // [128 rows][32 bf16] swizzled, dbuf
  const int m0 = blockIdx.x * 128;
  const int tid = threadIdx.x;
  const int lane = tid & 63;
  const int wid = tid >> 6;
  const int wm = wid & 1, wn = wid >> 1;
  const int lr = lane & 15;
  const int lg = lane >> 4;

#pragma unroll
  for (int it = 0; it < 16; ++it) {
    int c = wid * 16 + it;
    int cc = c * 64 + lane;
    int row = cc >> 5, slot = cc & 31;
    int src = slot ^ (row & 7);
    g2l16(A + (size_t)(m0 + row) * 256 + src * 8, (void*)(As + c * 1024));
  }
  __syncthreads();

  for (int nt = 0; nt < 2; ++nt) {
    const int n0 = nt * 128;
    f32x4 acc[4][4] = {};

#pragma unroll
    for (int it2 = 0; it2 < 2; ++it2) {
      int wc = wid * 2 + it2;
      int cc = wc * 64 + lane;
      int row = cc >> 2, slot = cc & 3;
      int sw = (row & 3) ^ ((row >> 3) & 3);
      g2l16(W + (size_t)(n0 + row) * 256 + ((slot ^ sw) * 8), (void*)(Bs[0] + wc * 1024));
    }
    __syncthreads();

    for (int ks = 0; ks < 8; ++ks) {
      const int cur = ks & 1;
      if (ks < 7) {
#pragma unroll
        for (int it2 = 0; it2 < 2; ++it2) {
          int wc = wid * 2 + it2;
          int cc = wc * 64 + lane;
          int row = cc >> 2, slot = cc & 3;
          int sw = (row & 3) ^ ((row >> 3) & 3);
          g2l16(W + (size_t)(n0 + row) * 256 + (ks + 1) * 32 + ((slot ^ sw) * 8),
                (void*)(Bs[cur ^ 1] + wc * 1024));
        }
      }
      bf16x8 a[4], b[4];
#pragma unroll
      for (int m = 0; m < 4; ++m) {
        int row = wm * 64 + m * 16 + lr;
        a[m] = *(const bf16x8*)(As + row * 512 + ((ks * 64 + lg * 16) ^ ((row & 7) << 4)));
      }
#pragma unroll
      for (int n = 0; n < 4; ++n) {
        int row = wn * 64 + n * 16 + lr;
        int sw = (row & 3) ^ ((row >> 3) & 3);
        b[n] = *(const bf16x8*)(Bs[cur] + row * 64 + ((lg * 16) ^ (sw << 4)));
      }
#pragma unroll
      for (int m = 0; m < 4; ++m)
#pragma unroll
        for (int n = 0; n < 4; ++n)
          acc[m][n] = __builtin_amdgcn_mfma_f32_16x16x32_bf16(a[m], b[n], acc[m][n], 0, 0, 0);
      __syncthreads();
    }

#pragma unroll
    for (int m = 0; m < 4; ++m) {
      int row = m0 + wm * 64 + m * 16 + lg * 4;
#pragma unroll
      for (int n = 0; n < 4; ++n) {
        int col = n0 + wn * 64 + n * 16 + lr;
        float bv = pb[col];
#pragma unroll
        for (int r = 0; r < 4; ++r)
          C[(size_t)(row + r) * 256 + col] = acc[m][n][r] + bv;
      }
    }
  }
}

// ---------------- launch ----------------
extern "C" void kernel_launch(void* const* d_in, const int* in_sizes, int n_in,
                              void* d_out, int out_size, void* d_ws, size_t ws_size,
                              hipStream_t stream) {
  const float* x      = (const float*)d_in[0];
  const float* mask   = (const float*)d_in[1];
  const float* pbt    = (const float*)d_in[2];
  const float* qkv_w  = (const float*)d_in[3];
  const float* proj_w = (const float*)d_in[4];
  const float* proj_b = (const float*)d_in[5];
  const int*   rpi    = (const int*)d_in[6];
  float* out = (float*)d_out;

  char* ws = (char*)d_ws;
  __bf16* qkv      = (__bf16*)(ws);                   // 16384*9408*2 = 308,281,344
  __bf16* y        = (__bf16*)(ws + 308281344);       // 200704*256*2 = 102,760,448
  __bf16* qkvw_b   = (__bf16*)(ws + 411041792);       // 393,216
  __bf16* projw_b  = (__bf16*)(ws + 411435008);       // 131,072
  float*  cmb      = (float*) (ws + 411566080);       // 256*8*98*128*4 = 102,760,448 (~514MB)

  int prep_n = 256 * 8 * NTOK * 32;                   // float4 count
  prep_kernel<<<(prep_n + 255) / 256, 256, 0, stream>>>(qkv_w, proj_w, pbt, rpi, mask,
                                                        qkvw_b, projw_b, cmb);
  gemm_qkv<<<MROWS / 128, 256, 0, stream>>>(x, qkvw_b, qkv);
  attn_kernel<<<NWIN * 8, 128, 0, stream>>>(qkv, cmb, y);
  gemm_proj<<<MROWS / 128, 256, 0, stream>>>(y, projw_b, proj_b, out);
}

// Round 25
// 493.896 us; speedup vs baseline: 1.1980x; 1.1980x over previous
//
#include <hip/hip_runtime.h>
#include <hip/hip_bf16.h>
#include <math.h>

typedef float f32x4 __attribute__((ext_vector_type(4)));
typedef __bf16 bf16x8 __attribute__((ext_vector_type(8)));

#define NTOK 98
#define NWIN 2048
#define NN (NTOK * NTOK)            // 9604
#define SCALE 0.17677669529663689f
#define MROWS (NWIN * NTOK)         // 200704
#define PSTRIDE 9408                // per-(win,h): q 3136 + k 3136 + v 3136 elems

// ---------------- async global->LDS 16B ----------------
__device__ __forceinline__ void g2l16(const void* g, void* l) {
  typedef __attribute__((address_space(1))) const unsigned int GU;
  typedef __attribute__((address_space(3))) unsigned int LU;
  __builtin_amdgcn_global_load_lds((GU*)g, (LU*)l, 16, 0, 0);
}

// ---------------- prep (vectorized): weights->bf16, cmb float4 ----------------
__global__ void prep_kernel(const float* __restrict__ qkv_w, const float* __restrict__ proj_w,
                            const float* __restrict__ pbt, const int* __restrict__ rpi,
                            const float* __restrict__ mask,
                            __bf16* __restrict__ qkvw_b, __bf16* __restrict__ projw_b,
                            float* __restrict__ cmb) {
  int i4 = blockIdx.x * 256 + threadIdx.x;
  if (i4 < 768 * 256 / 8) {
    const float* p = qkv_w + (size_t)i4 * 8;
    float4 f0 = *(const float4*)p;
    float4 f1 = *(const float4*)(p + 4);
    bf16x8 hv;
    hv[0] = (__bf16)f0.x; hv[1] = (__bf16)f0.y; hv[2] = (__bf16)f0.z; hv[3] = (__bf16)f0.w;
    hv[4] = (__bf16)f1.x; hv[5] = (__bf16)f1.y; hv[6] = (__bf16)f1.z; hv[7] = (__bf16)f1.w;
    *(bf16x8*)(qkvw_b + (size_t)i4 * 8) = hv;
  }
  if (i4 < 256 * 256 / 8) {
    const float* p = proj_w + (size_t)i4 * 8;
    float4 f0 = *(const float4*)p;
    float4 f1 = *(const float4*)(p + 4);
    bf16x8 hv;
    hv[0] = (__bf16)f0.x; hv[1] = (__bf16)f0.y; hv[2] = (__bf16)f0.z; hv[3] = (__bf16)f0.w;
    hv[4] = (__bf16)f1.x; hv[5] = (__bf16)f1.y; hv[6] = (__bf16)f1.z; hv[7] = (__bf16)f1.w;
    *(bf16x8*)(projw_b + (size_t)i4 * 8) = hv;
  }
  if (i4 < 256 * 8 * NTOK * 32) {
    int mh = i4 / (NTOK * 32);            // m*8 + h
    int rem = i4 - mh * (NTOK * 32);
    int row = rem >> 5, j4 = rem & 31;
    int j = j4 * 4;
    int m = mh >> 3, h = mh & 7;
    float4 v = {0.f, 0.f, 0.f, 0.f};
    if (j < NTOK) {
      const float* mrow = mask + (size_t)m * NN + row * NTOK;
      const int* rrow = rpi + row * NTOK;
#pragma unroll
      for (int c = 0; c < 4; ++c)
        if (j + c < NTOK) (&v.x)[c] = pbt[rrow[j + c] * 8 + h] + mrow[j + c];
    }
    *(float4*)(cmb + (size_t)(mh * NTOK + row) * 128 + j) = v;
  }
}

// ---------------- QKV GEMM: BM=64 (3 blocks/CU), A once, B dbuf BK=32 ----------------
__launch_bounds__(256)
__global__ void gemm_qkv(const float* __restrict__ A, const __bf16* __restrict__ W,
                         __bf16* __restrict__ C) {
  __shared__ __align__(16) char As[32768];       // [64 rows][256 bf16] swizzled
  __shared__ __align__(16) char Bs[2][8192];     // [128 rows][32 bf16] swizzled, dbuf
  const int m0 = blockIdx.x * 64;
  const int tid = threadIdx.x;
  const int lane = tid & 63;
  const int wid = tid >> 6;                      // 0..3, waves 1M x 4N (64x32 tile)
  const int wn = wid;
  const int lr = lane & 15;
  const int lg = lane >> 4;

  // stage A once: fp32 -> bf16 through regs, swizzled, K fully resident
  for (int c = tid; c < 64 * 32; c += 256) {
    int row = c >> 5, slot = c & 31;
    const float* ap = A + (size_t)(m0 + row) * 256 + slot * 8;
    float4 f0 = *(const float4*)ap;
    float4 f1 = *(const float4*)(ap + 4);
    bf16x8 hv;
    hv[0] = (__bf16)f0.x; hv[1] = (__bf16)f0.y; hv[2] = (__bf16)f0.z; hv[3] = (__bf16)f0.w;
    hv[4] = (__bf16)f1.x; hv[5] = (__bf16)f1.y; hv[6] = (__bf16)f1.z; hv[7] = (__bf16)f1.w;
    *(bf16x8*)(As + row * 512 + ((slot * 16) ^ ((row & 7) << 4))) = hv;
  }
  __syncthreads();

  for (int nt = 0; nt < 6; ++nt) {
    const int n0 = nt * 128;
    f32x4 acc[4][2] = {};

    // stage B k-step 0 into buf 0 (pre-swizzled source, linear dest)
#pragma unroll
    for (int it2 = 0; it2 < 2; ++it2) {
      int wc = wid * 2 + it2;
      int cc = wc * 64 + lane;
      int row = cc >> 2, slot = cc & 3;
      int sw = (row & 3) ^ ((row >> 3) & 3);
      g2l16(W + (size_t)(n0 + row) * 256 + ((slot ^ sw) * 8), (void*)(Bs[0] + wc * 1024));
    }
    __syncthreads();

    for (int ks = 0; ks < 8; ++ks) {
      const int cur = ks & 1;
      if (ks < 7) {
#pragma unroll
        for (int it2 = 0; it2 < 2; ++it2) {
          int wc = wid * 2 + it2;
          int cc = wc * 64 + lane;
          int row = cc >> 2, slot = cc & 3;
          int sw = (row & 3) ^ ((row >> 3) & 3);
          g2l16(W + (size_t)(n0 + row) * 256 + (ks + 1) * 32 + ((slot ^ sw) * 8),
                (void*)(Bs[cur ^ 1] + wc * 1024));
        }
      }
      bf16x8 a[4], b[2];
#pragma unroll
      for (int m = 0; m < 4; ++m) {
        int row = m * 16 + lr;
        a[m] = *(const bf16x8*)(As + row * 512 + ((ks * 64 + lg * 16) ^ ((row & 7) << 4)));
      }
#pragma unroll
      for (int n = 0; n < 2; ++n) {
        int row = wn * 32 + n * 16 + lr;
        int sw = (row & 3) ^ ((row >> 3) & 3);
        b[n] = *(const bf16x8*)(Bs[cur] + row * 64 + ((lg * 16) ^ (sw << 4)));
      }
#pragma unroll
      for (int m = 0; m < 4; ++m)
#pragma unroll
        for (int n = 0; n < 2; ++n)
          acc[m][n] = __builtin_amdgcn_mfma_f32_16x16x32_bf16(a[m], b[n], acc[m][n], 0, 0, 0);
      __syncthreads();
    }

    // epilogue for this nt: head-blocked, linear [tok][32] -> coalesced 32B stores
#pragma unroll
    for (int m = 0; m < 4; ++m)
#pragma unroll
      for (int r = 0; r < 4; ++r) {
        unsigned row = m0 + m * 16 + lg * 4 + r;
        unsigned win = row / NTOK;
        unsigned tok = row - win * NTOK;
#pragma unroll
        for (int n = 0; n < 2; ++n) {
          int col = n0 + wn * 32 + n * 16 + lr;
          int sec = col >> 8, dd = col & 255;
          int h = dd >> 5, d = dd & 31;
          C[(size_t)(win * 8 + h) * PSTRIDE + (size_t)sec * 3136 + tok * 32 + d] =
              (__bf16)acc[m][n][r];
        }
      }
  }
}

// ---------------- attention (R14): cmb float4 stream; VT in LDS; hoisted K frags ----------------
__launch_bounds__(128)
__global__ void attn_kernel(const __bf16* __restrict__ qkv, const float* __restrict__ cmb,
                            __bf16* __restrict__ y) {
  __shared__ __align__(16) char VTB[8192];      // VT [32 d][128 j] bf16, swizzled
  int bx = blockIdx.x;
  int lb = (bx & 7) * 2048 + (bx >> 3);         // win-major within each XCD
  const int win = lb >> 3, h = lb & 7;
  const int tid = threadIdx.x;
  const int lane = tid & 63, wv = tid >> 6;
  const int lr = lane & 15, lg = lane >> 4;
  const f32x4 fz = {0.f, 0.f, 0.f, 0.f};

  const __bf16* qw = qkv + (size_t)(win * 8 + h) * PSTRIDE;
  const __bf16* kw = qw + 3136;
  const __bf16* vw = qw + 6272;                 // v [tok][32]
  const float* cw = cmb + (size_t)((win & 255) * 8 + h) * (NTOK * 128);

  for (int c = tid; c < 512; c += 128) {
    int j = c & 127; int jc = j < NTOK ? j : NTOK - 1;
    int d8 = (c >> 7) << 3;
    bf16x8 vv = *(const bf16x8*)(vw + jc * 32 + d8);
#pragma unroll
    for (int e = 0; e < 8; ++e) {
      int d = d8 + e;
      *(__bf16*)(VTB + d * 256 + ((2 * j) ^ ((d & 7) << 4))) = vv[e];
    }
  }

  bf16x8 bk[7];
#pragma unroll
  for (int jt = 0; jt < 7; ++jt) {
    int brow = ((jt >> 1) << 5) + ((lr >> 2) << 3) + ((jt & 1) << 2) + (lr & 3);
    int browc = brow < NTOK ? brow : NTOK - 1;
    bk[jt] = *(const bf16x8*)(kw + browc * 32 + lg * 8);
  }
  __syncthreads();

  for (int it = wv; it < 7; it += 2) {
    const int i0 = it * 16;
    const int qrow = i0 + lr;
    const int qrowc = qrow < NTOK ? qrow : NTOK - 1;
    bf16x8 aq = *(const bf16x8*)(qw + qrowc * 32 + lg * 8);

    const float* cr = cw + qrowc * 128;
    float4 cv[7];
#pragma unroll
    for (int jt = 0; jt < 7; ++jt) {
      int kb = ((jt >> 1) << 5) + lg * 8 + ((jt & 1) << 2);
      cv[jt] = *(const float4*)(cr + kb);
    }

    f32x4 s[7];
#pragma unroll
    for (int jt = 0; jt < 7; ++jt)
      s[jt] = __builtin_amdgcn_mfma_f32_16x16x32_bf16(bk[jt], aq, fz, 0, 0, 0);

    float sv[7][4];
    float mx = -INFINITY;
#pragma unroll
    for (int jt = 0; jt < 7; ++jt) {
      int kb = ((jt >> 1) << 5) + lg * 8 + ((jt & 1) << 2);
#pragma unroll
      for (int r = 0; r < 4; ++r) {
        float xv = (kb + r < NTOK) ? fmaf(SCALE, s[jt][r], (&cv[jt].x)[r]) : -INFINITY;
        sv[jt][r] = xv;
        mx = fmaxf(mx, xv);
      }
    }
    mx = fmaxf(mx, __shfl_xor(mx, 16));
    mx = fmaxf(mx, __shfl_xor(mx, 32));
    float sum = 0.f;
#pragma unroll
    for (int jt = 0; jt < 7; ++jt)
#pragma unroll
      for (int r = 0; r < 4; ++r) {
        float p = __expf(sv[jt][r] - mx);
        sv[jt][r] = p;
        sum += p;
      }
    sum += __shfl_xor(sum, 16);
    sum += __shfl_xor(sum, 32);
    const float rinv = 1.f / sum;

    bf16x8 pa[4];
#pragma unroll
    for (int ks = 0; ks < 4; ++ks)
#pragma unroll
      for (int e = 0; e < 8; ++e) {
        int jt = 2 * ks + (e >> 2);
        pa[ks][e] = (jt < 7) ? (__bf16)sv[jt][e & 3] : (__bf16)0.f;
      }

    float rv[4];
#pragma unroll
    for (int r = 0; r < 4; ++r) rv[r] = __shfl(rinv, lg * 4 + r);

#pragma unroll
    for (int dt = 0; dt < 2; ++dt) {
      f32x4 o = fz;
#pragma unroll
      for (int ks = 0; ks < 4; ++ks) {
        int vrow = dt * 16 + lr;
        bf16x8 vb = *(const bf16x8*)(VTB + vrow * 256 + ((ks * 64 + lg * 16) ^ ((vrow & 7) << 4)));
        o = __builtin_amdgcn_mfma_f32_16x16x32_bf16(pa[ks], vb, o, 0, 0, 0);
      }
#pragma unroll
      for (int r = 0; r < 4; ++r) {
        int row = i0 + lg * 4 + r;
        if (row < NTOK)
          y[((size_t)win * NTOK + row) * 256 + h * 32 + dt * 16 + lr] = (__bf16)(o[r] * rv[r]);
      }
    }
  }
}

// ---------------- proj GEMM (R20): A(y) staged once, 2 N-tiles per block, B dbuf BK=32 ----------------
__launch_bounds__(256)
__global__ void gemm_proj(const __bf16* __restrict__ A, const __bf16* __restrict__ W,
                          const float* __restrict__ pb, float* __restrict__ C) {
  __shared__ __align__(16) char As[65536];       // [128 rows][256 bf16] swizzled
  __shared__ __align__(16) char Bs[2][8192];     // [128 rows][32 bf16] swizzled, dbuf
  const int m0 = blockIdx.x * 128;
  const int tid = threadIdx.x;
  const int lane = tid & 63;
  const int wid = tid >> 6;
  const int wm = wid & 1, wn = wid >> 1;
  const int lr = lane & 15;
  const int lg = lane >> 4;

#pragma unroll
  for (int it = 0; it < 16; ++it) {
    int c = wid * 16 + it;
    int cc = c * 64 + lane;
    int row = cc >> 5, slot = cc & 31;
    int src = slot ^ (row & 7);
    g2l16(A + (size_t)(m0 + row) * 256 + src * 8, (void*)(As + c * 1024));
  }
  __syncthreads();

  for (int nt = 0; nt < 2; ++nt) {
    const int n0 = nt * 128;
    f32x4 acc[4][4] = {};

#pragma unroll
    for (int it2 = 0; it2 < 2; ++it2) {
      int wc = wid * 2 + it2;
      int cc = wc * 64 + lane;
      int row = cc >> 2, slot = cc & 3;
      int sw = (row & 3) ^ ((row >> 3) & 3);
      g2l16(W + (size_t)(n0 + row) * 256 + ((slot ^ sw) * 8), (void*)(Bs[0] + wc * 1024));
    }
    __syncthreads();

    for (int ks = 0; ks < 8; ++ks) {
      const int cur = ks & 1;
      if (ks < 7) {
#pragma unroll
        for (int it2 = 0; it2 < 2; ++it2) {
          int wc = wid * 2 + it2;
          int cc = wc * 64 + lane;
          int row = cc >> 2, slot = cc & 3;
          int sw = (row & 3) ^ ((row >> 3) & 3);
          g2l16(W + (size_t)(n0 + row) * 256 + (ks + 1) * 32 + ((slot ^ sw) * 8),
                (void*)(Bs[cur ^ 1] + wc * 1024));
        }
      }
      bf16x8 a[4], b[4];
#pragma unroll
      for (int m = 0; m < 4; ++m) {
        int row = wm * 64 + m * 16 + lr;
        a[m] = *(const bf16x8*)(As + row * 512 + ((ks * 64 + lg * 16) ^ ((row & 7) << 4)));
      }
#pragma unroll
      for (int n = 0; n < 4; ++n) {
        int row = wn * 64 + n * 16 + lr;
        int sw = (row & 3) ^ ((row >> 3) & 3);
        b[n] = *(const bf16x8*)(Bs[cur] + row * 64 + ((lg * 16) ^ (sw << 4)));
      }
#pragma unroll
      for (int m = 0; m < 4; ++m)
#pragma unroll
        for (int n = 0; n < 4; ++n)
          acc[m][n] = __builtin_amdgcn_mfma_f32_16x16x32_bf16(a[m], b[n], acc[m][n], 0, 0, 0);
      __syncthreads();
    }

#pragma unroll
    for (int m = 0; m < 4; ++m) {
      int row = m0 + wm * 64 + m * 16 + lg * 4;
#pragma unroll
      for (int n = 0; n < 4; ++n) {
        int col = n0 + wn * 64 + n * 16 + lr;
        float bv = pb[col];
#pragma unroll
        for (int r = 0; r < 4; ++r)
          C[(size_t)(row + r) * 256 + col] = acc[m][n][r] + bv;
      }
    }
  }
}

// ---------------- launch ----------------
extern "C" void kernel_launch(void* const* d_in, const int* in_sizes, int n_in,
                              void* d_out, int out_size, void* d_ws, size_t ws_size,
                              hipStream_t stream) {
  const float* x      = (const float*)d_in[0];
  const float* mask   = (const float*)d_in[1];
  const float* pbt    = (const float*)d_in[2];
  const float* qkv_w  = (const float*)d_in[3];
  const float* proj_w = (const float*)d_in[4];
  const float* proj_b = (const float*)d_in[5];
  const int*   rpi    = (const int*)d_in[6];
  float* out = (float*)d_out;

  char* ws = (char*)d_ws;
  __bf16* qkv      = (__bf16*)(ws);                   // 16384*9408*2 = 308,281,344
  __bf16* y        = (__bf16*)(ws + 308281344);       // 200704*256*2 = 102,760,448
  __bf16* qkvw_b   = (__bf16*)(ws + 411041792);       // 393,216
  __bf16* projw_b  = (__bf16*)(ws + 411435008);       // 131,072
  float*  cmb      = (float*) (ws + 411566080);       // 256*8*98*128*4 = 102,760,448 (~514MB)

  int prep_n = 256 * 8 * NTOK * 32;                   // float4 count
  prep_kernel<<<(prep_n + 255) / 256, 256, 0, stream>>>(qkv_w, proj_w, pbt, rpi, mask,
                                                        qkvw_b, projw_b, cmb);
  gemm_qkv<<<MROWS / 64, 256, 0, stream>>>(x, qkvw_b, qkv);
  attn_kernel<<<NWIN * 8, 128, 0, stream>>>(qkv, cmb, y);
  gemm_proj<<<MROWS / 128, 256, 0, stream>>>(y, projw_b, proj_b, out);
}

// Round 26
// 455.713 us; speedup vs baseline: 1.2984x; 1.0838x over previous
//
#include <hip/hip_runtime.h>
#include <hip/hip_bf16.h>
#include <math.h>

typedef float f32x4 __attribute__((ext_vector_type(4)));
typedef __bf16 bf16x8 __attribute__((ext_vector_type(8)));
typedef _Float16 hf4 __attribute__((ext_vector_type(4)));

#define NTOK 98
#define NWIN 2048
#define NN (NTOK * NTOK)            // 9604
#define SCALE 0.17677669529663689f
#define MROWS (NWIN * NTOK)         // 200704
#define PSTRIDE 9408                // per-(win,h): q 3136 + k 3136 + v 3136 elems

// ---------------- async global->LDS 16B ----------------
__device__ __forceinline__ void g2l16(const void* g, void* l) {
  typedef __attribute__((address_space(1))) const unsigned int GU;
  typedef __attribute__((address_space(3))) unsigned int LU;
  __builtin_amdgcn_global_load_lds((GU*)g, (LU*)l, 16, 0, 0);
}

// ---------------- prep (vectorized): weights->bf16, cmb fp16 ----------------
__global__ void prep_kernel(const float* __restrict__ qkv_w, const float* __restrict__ proj_w,
                            const float* __restrict__ pbt, const int* __restrict__ rpi,
                            const float* __restrict__ mask,
                            __bf16* __restrict__ qkvw_b, __bf16* __restrict__ projw_b,
                            _Float16* __restrict__ cmb) {
  int i4 = blockIdx.x * 256 + threadIdx.x;
  if (i4 < 768 * 256 / 8) {
    const float* p = qkv_w + (size_t)i4 * 8;
    float4 f0 = *(const float4*)p;
    float4 f1 = *(const float4*)(p + 4);
    bf16x8 hv;
    hv[0] = (__bf16)f0.x; hv[1] = (__bf16)f0.y; hv[2] = (__bf16)f0.z; hv[3] = (__bf16)f0.w;
    hv[4] = (__bf16)f1.x; hv[5] = (__bf16)f1.y; hv[6] = (__bf16)f1.z; hv[7] = (__bf16)f1.w;
    *(bf16x8*)(qkvw_b + (size_t)i4 * 8) = hv;
  }
  if (i4 < 256 * 256 / 8) {
    const float* p = proj_w + (size_t)i4 * 8;
    float4 f0 = *(const float4*)p;
    float4 f1 = *(const float4*)(p + 4);
    bf16x8 hv;
    hv[0] = (__bf16)f0.x; hv[1] = (__bf16)f0.y; hv[2] = (__bf16)f0.z; hv[3] = (__bf16)f0.w;
    hv[4] = (__bf16)f1.x; hv[5] = (__bf16)f1.y; hv[6] = (__bf16)f1.z; hv[7] = (__bf16)f1.w;
    *(bf16x8*)(projw_b + (size_t)i4 * 8) = hv;
  }
  if (i4 < 256 * 8 * NTOK * 32) {
    int mh = i4 / (NTOK * 32);            // m*8 + h
    int rem = i4 - mh * (NTOK * 32);
    int row = rem >> 5, j4 = rem & 31;
    int j = j4 * 4;
    int m = mh >> 3, h = mh & 7;
    hf4 v = {0, 0, 0, 0};
    if (j < NTOK) {
      const float* mrow = mask + (size_t)m * NN + row * NTOK;
      const int* rrow = rpi + row * NTOK;
#pragma unroll
      for (int c = 0; c < 4; ++c)
        if (j + c < NTOK) v[c] = (_Float16)(pbt[rrow[j + c] * 8 + h] + mrow[j + c]);
    }
    *(hf4*)(cmb + (size_t)(mh * NTOK + row) * 128 + j) = v;
  }
}

// ---------------- QKV GEMM (R25): BM=64 (3 blocks/CU), A once, B dbuf BK=32 ----------------
__launch_bounds__(256)
__global__ void gemm_qkv(const float* __restrict__ A, const __bf16* __restrict__ W,
                         __bf16* __restrict__ C) {
  __shared__ __align__(16) char As[32768];       // [64 rows][256 bf16] swizzled
  __shared__ __align__(16) char Bs[2][8192];     // [128 rows][32 bf16] swizzled, dbuf
  const int m0 = blockIdx.x * 64;
  const int tid = threadIdx.x;
  const int lane = tid & 63;
  const int wid = tid >> 6;                      // 0..3, waves 1M x 4N (64x32 tile)
  const int wn = wid;
  const int lr = lane & 15;
  const int lg = lane >> 4;

  for (int c = tid; c < 64 * 32; c += 256) {
    int row = c >> 5, slot = c & 31;
    const float* ap = A + (size_t)(m0 + row) * 256 + slot * 8;
    float4 f0 = *(const float4*)ap;
    float4 f1 = *(const float4*)(ap + 4);
    bf16x8 hv;
    hv[0] = (__bf16)f0.x; hv[1] = (__bf16)f0.y; hv[2] = (__bf16)f0.z; hv[3] = (__bf16)f0.w;
    hv[4] = (__bf16)f1.x; hv[5] = (__bf16)f1.y; hv[6] = (__bf16)f1.z; hv[7] = (__bf16)f1.w;
    *(bf16x8*)(As + row * 512 + ((slot * 16) ^ ((row & 7) << 4))) = hv;
  }
  __syncthreads();

  for (int nt = 0; nt < 6; ++nt) {
    const int n0 = nt * 128;
    f32x4 acc[4][2] = {};

#pragma unroll
    for (int it2 = 0; it2 < 2; ++it2) {
      int wc = wid * 2 + it2;
      int cc = wc * 64 + lane;
      int row = cc >> 2, slot = cc & 3;
      int sw = (row & 3) ^ ((row >> 3) & 3);
      g2l16(W + (size_t)(n0 + row) * 256 + ((slot ^ sw) * 8), (void*)(Bs[0] + wc * 1024));
    }
    __syncthreads();

    for (int ks = 0; ks < 8; ++ks) {
      const int cur = ks & 1;
      if (ks < 7) {
#pragma unroll
        for (int it2 = 0; it2 < 2; ++it2) {
          int wc = wid * 2 + it2;
          int cc = wc * 64 + lane;
          int row = cc >> 2, slot = cc & 3;
          int sw = (row & 3) ^ ((row >> 3) & 3);
          g2l16(W + (size_t)(n0 + row) * 256 + (ks + 1) * 32 + ((slot ^ sw) * 8),
                (void*)(Bs[cur ^ 1] + wc * 1024));
        }
      }
      bf16x8 a[4], b[2];
#pragma unroll
      for (int m = 0; m < 4; ++m) {
        int row = m * 16 + lr;
        a[m] = *(const bf16x8*)(As + row * 512 + ((ks * 64 + lg * 16) ^ ((row & 7) << 4)));
      }
#pragma unroll
      for (int n = 0; n < 2; ++n) {
        int row = wn * 32 + n * 16 + lr;
        int sw = (row & 3) ^ ((row >> 3) & 3);
        b[n] = *(const bf16x8*)(Bs[cur] + row * 64 + ((lg * 16) ^ (sw << 4)));
      }
#pragma unroll
      for (int m = 0; m < 4; ++m)
#pragma unroll
        for (int n = 0; n < 2; ++n)
          acc[m][n] = __builtin_amdgcn_mfma_f32_16x16x32_bf16(a[m], b[n], acc[m][n], 0, 0, 0);
      __syncthreads();
    }

#pragma unroll
    for (int m = 0; m < 4; ++m)
#pragma unroll
      for (int r = 0; r < 4; ++r) {
        unsigned row = m0 + m * 16 + lg * 4 + r;
        unsigned win = row / NTOK;
        unsigned tok = row - win * NTOK;
#pragma unroll
        for (int n = 0; n < 2; ++n) {
          int col = n0 + wn * 32 + n * 16 + lr;
          int sec = col >> 8, dd = col & 255;
          int h = dd >> 5, d = dd & 31;
          C[(size_t)(win * 8 + h) * PSTRIDE + (size_t)sec * 3136 + tok * 32 + d] =
              (__bf16)acc[m][n][r];
        }
      }
  }
}

// ---------------- attention: cmb fp16 stream; VT in LDS; hoisted K frags ----------------
__launch_bounds__(128)
__global__ void attn_kernel(const __bf16* __restrict__ qkv, const _Float16* __restrict__ cmb,
                            __bf16* __restrict__ y) {
  __shared__ __align__(16) char VTB[8192];      // VT [32 d][128 j] bf16, swizzled
  int bx = blockIdx.x;
  int lb = (bx & 7) * 2048 + (bx >> 3);         // win-major within each XCD
  const int win = lb >> 3, h = lb & 7;
  const int tid = threadIdx.x;
  const int lane = tid & 63, wv = tid >> 6;
  const int lr = lane & 15, lg = lane >> 4;
  const f32x4 fz = {0.f, 0.f, 0.f, 0.f};

  const __bf16* qw = qkv + (size_t)(win * 8 + h) * PSTRIDE;
  const __bf16* kw = qw + 3136;
  const __bf16* vw = qw + 6272;                 // v [tok][32]
  const _Float16* cw = cmb + (size_t)((win & 255) * 8 + h) * (NTOK * 128);

  for (int c = tid; c < 512; c += 128) {
    int j = c & 127; int jc = j < NTOK ? j : NTOK - 1;
    int d8 = (c >> 7) << 3;
    bf16x8 vv = *(const bf16x8*)(vw + jc * 32 + d8);
#pragma unroll
    for (int e = 0; e < 8; ++e) {
      int d = d8 + e;
      *(__bf16*)(VTB + d * 256 + ((2 * j) ^ ((d & 7) << 4))) = vv[e];
    }
  }

  bf16x8 bk[7];
#pragma unroll
  for (int jt = 0; jt < 7; ++jt) {
    int brow = ((jt >> 1) << 5) + ((lr >> 2) << 3) + ((jt & 1) << 2) + (lr & 3);
    int browc = brow < NTOK ? brow : NTOK - 1;
    bk[jt] = *(const bf16x8*)(kw + browc * 32 + lg * 8);
  }
  __syncthreads();

  for (int it = wv; it < 7; it += 2) {
    const int i0 = it * 16;
    const int qrow = i0 + lr;
    const int qrowc = qrow < NTOK ? qrow : NTOK - 1;
    bf16x8 aq = *(const bf16x8*)(qw + qrowc * 32 + lg * 8);

    const _Float16* cr = cw + qrowc * 128;
    hf4 cv[7];
#pragma unroll
    for (int jt = 0; jt < 7; ++jt) {
      int kb = ((jt >> 1) << 5) + lg * 8 + ((jt & 1) << 2);
      cv[jt] = *(const hf4*)(cr + kb);
    }

    f32x4 s[7];
#pragma unroll
    for (int jt = 0; jt < 7; ++jt)
      s[jt] = __builtin_amdgcn_mfma_f32_16x16x32_bf16(bk[jt], aq, fz, 0, 0, 0);

    float sv[7][4];
    float mx = -INFINITY;
#pragma unroll
    for (int jt = 0; jt < 7; ++jt) {
      int kb = ((jt >> 1) << 5) + lg * 8 + ((jt & 1) << 2);
#pragma unroll
      for (int r = 0; r < 4; ++r) {
        float xv = (kb + r < NTOK) ? fmaf(SCALE, s[jt][r], (float)cv[jt][r]) : -INFINITY;
        sv[jt][r] = xv;
        mx = fmaxf(mx, xv);
      }
    }
    mx = fmaxf(mx, __shfl_xor(mx, 16));
    mx = fmaxf(mx, __shfl_xor(mx, 32));
    float sum = 0.f;
#pragma unroll
    for (int jt = 0; jt < 7; ++jt)
#pragma unroll
      for (int r = 0; r < 4; ++r) {
        float p = __expf(sv[jt][r] - mx);
        sv[jt][r] = p;
        sum += p;
      }
    sum += __shfl_xor(sum, 16);
    sum += __shfl_xor(sum, 32);
    const float rinv = 1.f / sum;

    bf16x8 pa[4];
#pragma unroll
    for (int ks = 0; ks < 4; ++ks)
#pragma unroll
      for (int e = 0; e < 8; ++e) {
        int jt = 2 * ks + (e >> 2);
        pa[ks][e] = (jt < 7) ? (__bf16)sv[jt][e & 3] : (__bf16)0.f;
      }

    float rv[4];
#pragma unroll
    for (int r = 0; r < 4; ++r) rv[r] = __shfl(rinv, lg * 4 + r);

#pragma unroll
    for (int dt = 0; dt < 2; ++dt) {
      f32x4 o = fz;
#pragma unroll
      for (int ks = 0; ks < 4; ++ks) {
        int vrow = dt * 16 + lr;
        bf16x8 vb = *(const bf16x8*)(VTB + vrow * 256 + ((ks * 64 + lg * 16) ^ ((vrow & 7) << 4)));
        o = __builtin_amdgcn_mfma_f32_16x16x32_bf16(pa[ks], vb, o, 0, 0, 0);
      }
#pragma unroll
      for (int r = 0; r < 4; ++r) {
        int row = i0 + lg * 4 + r;
        if (row < NTOK)
          y[((size_t)win * NTOK + row) * 256 + h * 32 + dt * 16 + lr] = (__bf16)(o[r] * rv[r]);
      }
    }
  }
}

// ---------------- proj GEMM (R20): A(y) staged once, 2 N-tiles per block, B dbuf BK=32 ----------------
__launch_bounds__(256)
__global__ void gemm_proj(const __bf16* __restrict__ A, const __bf16* __restrict__ W,
                          const float* __restrict__ pb, float* __restrict__ C) {
  __shared__ __align__(16) char As[65536];       // [128 rows][256 bf16] swizzled
  __shared__ __align__(16) char Bs[2][8192];     // [128 rows][32 bf16] swizzled, dbuf
  const int m0 = blockIdx.x * 128;
  const int tid = threadIdx.x;
  const int lane = tid & 63;
  const int wid = tid >> 6;
  const int wm = wid & 1, wn = wid >> 1;
  const int lr = lane & 15;
  const int lg = lane >> 4;

#pragma unroll
  for (int it = 0; it < 16; ++it) {
    int c = wid * 16 + it;
    int cc = c * 64 + lane;
    int row = cc >> 5, slot = cc & 31;
    int src = slot ^ (row & 7);
    g2l16(A + (size_t)(m0 + row) * 256 + src * 8, (void*)(As + c * 1024));
  }
  __syncthreads();

  for (int nt = 0; nt < 2; ++nt) {
    const int n0 = nt * 128;
    f32x4 acc[4][4] = {};

#pragma unroll
    for (int it2 = 0; it2 < 2; ++it2) {
      int wc = wid * 2 + it2;
      int cc = wc * 64 + lane;
      int row = cc >> 2, slot = cc & 3;
      int sw = (row & 3) ^ ((row >> 3) & 3);
      g2l16(W + (size_t)(n0 + row) * 256 + ((slot ^ sw) * 8), (void*)(Bs[0] + wc * 1024));
    }
    __syncthreads();

    for (int ks = 0; ks < 8; ++ks) {
      const int cur = ks & 1;
      if (ks < 7) {
#pragma unroll
        for (int it2 = 0; it2 < 2; ++it2) {
          int wc = wid * 2 + it2;
          int cc = wc * 64 + lane;
          int row = cc >> 2, slot = cc & 3;
          int sw = (row & 3) ^ ((row >> 3) & 3);
          g2l16(W + (size_t)(n0 + row) * 256 + (ks + 1) * 32 + ((slot ^ sw) * 8),
                (void*)(Bs[cur ^ 1] + wc * 1024));
        }
      }
      bf16x8 a[4], b[4];
#pragma unroll
      for (int m = 0; m < 4; ++m) {
        int row = wm * 64 + m * 16 + lr;
        a[m] = *(const bf16x8*)(As + row * 512 + ((ks * 64 + lg * 16) ^ ((row & 7) << 4)));
      }
#pragma unroll
      for (int n = 0; n < 4; ++n) {
        int row = wn * 64 + n * 16 + lr;
        int sw = (row & 3) ^ ((row >> 3) & 3);
        b[n] = *(const bf16x8*)(Bs[cur] + row * 64 + ((lg * 16) ^ (sw << 4)));
      }
#pragma unroll
      for (int m = 0; m < 4; ++m)
#pragma unroll
        for (int n = 0; n < 4; ++n)
          acc[m][n] = __builtin_amdgcn_mfma_f32_16x16x32_bf16(a[m], b[n], acc[m][n], 0, 0, 0);
      __syncthreads();
    }

#pragma unroll
    for (int m = 0; m < 4; ++m) {
      int row = m0 + wm * 64 + m * 16 + lg * 4;
#pragma unroll
      for (int n = 0; n < 4; ++n) {
        int col = n0 + wn * 64 + n * 16 + lr;
        float bv = pb[col];
#pragma unroll
        for (int r = 0; r < 4; ++r)
          C[(size_t)(row + r) * 256 + col] = acc[m][n][r] + bv;
      }
    }
  }
}

// ---------------- launch ----------------
extern "C" void kernel_launch(void* const* d_in, const int* in_sizes, int n_in,
                              void* d_out, int out_size, void* d_ws, size_t ws_size,
                              hipStream_t stream) {
  const float* x      = (const float*)d_in[0];
  const float* mask   = (const float*)d_in[1];
  const float* pbt    = (const float*)d_in[2];
  const float* qkv_w  = (const float*)d_in[3];
  const float* proj_w = (const float*)d_in[4];
  const float* proj_b = (const float*)d_in[5];
  const int*   rpi    = (const int*)d_in[6];
  float* out = (float*)d_out;

  char* ws = (char*)d_ws;
  __bf16*    qkv     = (__bf16*)(ws);                 // 16384*9408*2 = 308,281,344
  __bf16*    y       = (__bf16*)(ws + 308281344);     // 200704*256*2 = 102,760,448
  __bf16*    qkvw_b  = (__bf16*)(ws + 411041792);     // 393,216
  __bf16*    projw_b = (__bf16*)(ws + 411435008);     // 131,072
  _Float16*  cmb     = (_Float16*)(ws + 411566080);   // 256*8*98*128*2 = 51,380,224 (~463MB)

  int prep_n = 256 * 8 * NTOK * 32;                   // hf4 count
  prep_kernel<<<(prep_n + 255) / 256, 256, 0, stream>>>(qkv_w, proj_w, pbt, rpi, mask,
                                                        qkvw_b, projw_b, cmb);
  gemm_qkv<<<MROWS / 64, 256, 0, stream>>>(x, qkvw_b, qkv);
  attn_kernel<<<NWIN * 8, 128, 0, stream>>>(qkv, cmb, y);
  gemm_proj<<<MROWS / 128, 256, 0, stream>>>(y, projw_b, proj_b, out);
}